// Round 6
// baseline (3792.771 us; speedup 1.0000x reference)
//
#include <hip/hip_runtime.h>

constexpr int B_ = 8, E_ = 512, F_ = 1024, T_ = 2048, R_ = 10, L_ = 5;
constexpr int NTRI = 55;
constexpr int EW = E_ / 32;  // omega words per row = 16

typedef __attribute__((ext_vector_type(4))) float f32x4;
typedef __attribute__((ext_vector_type(8))) short short8v;

__device__ __forceinline__ float bf2f(unsigned short h) {
  return __uint_as_float(((unsigned)h) << 16);
}
__device__ __forceinline__ unsigned short f2bf(float v) {
  unsigned u = __float_as_uint(v);
  u = u + 0x7fffu + ((u >> 16) & 1u);
  return (unsigned short)(u >> 16);
}
__device__ __forceinline__ void split2(float v, unsigned short& h,
                                       unsigned short& l) {
  h = f2bf(v);
  l = f2bf(v - bf2f(h));
}
__device__ __forceinline__ float sigmoidf_(float v) {
  return 1.0f / (1.0f + expf(-v));
}

// ---------------------------------------------------------------------------
// 10x10 SPD solve, unrolled Cholesky, packed lower-tri
// ---------------------------------------------------------------------------
__device__ __forceinline__ void solve10(float M[NTRI], const float rhs[R_],
                                        float lam, float x[R_]) {
#pragma unroll
  for (int j = 0; j < R_; j++) M[j * (j + 1) / 2 + j] += lam;
#pragma unroll
  for (int j = 0; j < R_; j++) {
    float s = M[j * (j + 1) / 2 + j];
#pragma unroll
    for (int k = 0; k < j; k++) {
      float l = M[j * (j + 1) / 2 + k];
      s -= l * l;
    }
    s = fmaxf(s, 1e-30f);
    float d = sqrtf(s);
    float inv = 1.0f / d;
    M[j * (j + 1) / 2 + j] = d;
#pragma unroll
    for (int i = j + 1; i < R_; i++) {
      float s2 = M[i * (i + 1) / 2 + j];
#pragma unroll
      for (int k = 0; k < j; k++)
        s2 -= M[i * (i + 1) / 2 + k] * M[j * (j + 1) / 2 + k];
      M[i * (i + 1) / 2 + j] = s2 * inv;
    }
  }
  float y[R_];
#pragma unroll
  for (int i = 0; i < R_; i++) {
    float s = rhs[i];
#pragma unroll
    for (int k = 0; k < i; k++) s -= M[i * (i + 1) / 2 + k] * y[k];
    y[i] = s / M[i * (i + 1) / 2 + i];
  }
#pragma unroll
  for (int ii = R_ - 1; ii >= 0; ii--) {
    float s = y[ii];
#pragma unroll
    for (int k = ii + 1; k < R_; k++) s -= M[k * (k + 1) / 2 + ii] * x[k];
    x[ii] = s / M[ii * (ii + 1) / 2 + ii];
  }
}

// ---------------------------------------------------------------------------
// err GEMM: C[t,e] = sum_f AT[t,f]*Rm[e,f]; epilogue err = YOm - om*C,
// written as hi/lo bf16 planes. BM=BN=128, BK=32, 4 waves.
// ---------------------------------------------------------------------------
__global__ __launch_bounds__(256, 2) void gemm_err(
    const unsigned short* __restrict__ AHp, const unsigned short* __restrict__ ALp,
    const unsigned short* __restrict__ BHp, const unsigned short* __restrict__ BLp,
    const unsigned short* __restrict__ YHp, const unsigned short* __restrict__ YLp,
    const unsigned* __restrict__ omb, unsigned short* __restrict__ eHp,
    unsigned short* __restrict__ eLp) {
  constexpr int K = F_;
  __shared__ unsigned short AsH[4096], AsL[4096], BsH[4096], BsL[4096];
  int b = blockIdx.z, tid = threadIdx.x;
  int m0 = blockIdx.y * 128, n0 = blockIdx.x * 128;
  const unsigned short* AH = AHp + (long)b * T_ * F_;
  const unsigned short* AL = ALp + (long)b * T_ * F_;
  const unsigned short* BH = BHp + (long)b * E_ * F_;
  const unsigned short* BL = BLp + (long)b * E_ * F_;
  int lr = tid & 15, lh = (tid >> 4) & 3, wv = tid >> 6, wr = wv >> 1,
      wc = wv & 1;
  int srow = tid >> 2, sslot = tid & 3;

  f32x4 acc[4][4];
#pragma unroll
  for (int i = 0; i < 4; i++)
#pragma unroll
    for (int j = 0; j < 4; j++) acc[i][j] = {0.f, 0.f, 0.f, 0.f};

  uint4 ld[8];
#pragma unroll
  for (int j = 0; j < 2; j++) {
    ld[j] = *(const uint4*)&AH[(long)(m0 + srow + 64 * j) * K + sslot * 8];
    ld[2 + j] = *(const uint4*)&AL[(long)(m0 + srow + 64 * j) * K + sslot * 8];
    ld[4 + j] = *(const uint4*)&BH[(long)(n0 + srow + 64 * j) * K + sslot * 8];
    ld[6 + j] = *(const uint4*)&BL[(long)(n0 + srow + 64 * j) * K + sslot * 8];
  }
  for (int kt = 0; kt < K; kt += 32) {
#pragma unroll
    for (int j = 0; j < 2; j++) {
      int li = (srow + 64 * j) * 32 + sslot * 8;
      *(uint4*)&AsH[li] = ld[j];
      *(uint4*)&AsL[li] = ld[2 + j];
      *(uint4*)&BsH[li] = ld[4 + j];
      *(uint4*)&BsL[li] = ld[6 + j];
    }
    __syncthreads();
    if (kt + 32 < K) {
      int k1 = kt + 32;
#pragma unroll
      for (int j = 0; j < 2; j++) {
        ld[j] = *(const uint4*)&AH[(long)(m0 + srow + 64 * j) * K + k1 + sslot * 8];
        ld[2 + j] = *(const uint4*)&AL[(long)(m0 + srow + 64 * j) * K + k1 + sslot * 8];
        ld[4 + j] = *(const uint4*)&BH[(long)(n0 + srow + 64 * j) * K + k1 + sslot * 8];
        ld[6 + j] = *(const uint4*)&BL[(long)(n0 + srow + 64 * j) * K + k1 + sslot * 8];
      }
    }
    short8v aH[4], aL[4];
#pragma unroll
    for (int mf = 0; mf < 4; mf++) {
      int ml = wr * 64 + mf * 16 + lr;
      aH[mf] = *(const short8v*)&AsH[ml * 32 + lh * 8];
      aL[mf] = *(const short8v*)&AsL[ml * 32 + lh * 8];
    }
#pragma unroll
    for (int nf = 0; nf < 4; nf++) {
      int nl = wc * 64 + nf * 16 + lr;
      short8v bH = *(const short8v*)&BsH[nl * 32 + lh * 8];
      short8v bL = *(const short8v*)&BsL[nl * 32 + lh * 8];
#pragma unroll
      for (int mf = 0; mf < 4; mf++) {
        acc[mf][nf] = __builtin_amdgcn_mfma_f32_16x16x32_bf16(aH[mf], bH,
                                                              acc[mf][nf], 0, 0, 0);
        acc[mf][nf] = __builtin_amdgcn_mfma_f32_16x16x32_bf16(aH[mf], bL,
                                                              acc[mf][nf], 0, 0, 0);
        acc[mf][nf] = __builtin_amdgcn_mfma_f32_16x16x32_bf16(aL[mf], bH,
                                                              acc[mf][nf], 0, 0, 0);
      }
    }
    __syncthreads();
  }
#pragma unroll
  for (int mf = 0; mf < 4; mf++)
#pragma unroll
    for (int nf = 0; nf < 4; nf++)
#pragma unroll
      for (int r = 0; r < 4; r++) {
        int m = m0 + wr * 64 + mf * 16 + lh * 4 + r;
        int n = n0 + wc * 64 + nf * 16 + lr;
        long row = (long)b * T_ + m;
        long idx = row * E_ + n;
        float y = bf2f(YHp[idx]) + bf2f(YLp[idx]);
        unsigned w = omb[row * EW + (n >> 5)];
        float om = ((w >> (n & 31)) & 1) ? 1.f : 0.f;
        float er = y - om * acc[mf][nf][r];
        unsigned short h, l;
        split2(er, h, l);
        eHp[idx] = h;
        eLp[idx] = l;
      }
}

// ---------------------------------------------------------------------------
// Fused A-update GEMM: accC[t,f] = sum_e err[t,e]*Rt[f,e] (3-MFMA split),
// accS[t,f] = sum_e om[t,e]*R2[f,e] (2 MFMA: om exact * R2 hi/lo planes).
// Epilogue: soft-threshold BSCA step, A planes updated in place.
// ---------------------------------------------------------------------------
template <int S0>
__global__ __launch_bounds__(256, 2) void gemm_aupd(
    const unsigned short* __restrict__ eHp, const unsigned short* __restrict__ eLp,
    const unsigned* __restrict__ omb, const unsigned short* __restrict__ RtHp,
    const unsigned short* __restrict__ RtLp, const unsigned short* __restrict__ R2Hp,
    const unsigned short* __restrict__ R2Lp,
    unsigned short* __restrict__ AHp, unsigned short* __restrict__ ALp,
    const float* __restrict__ mu_log, const float* __restrict__ sk, int step) {
  constexpr int K = E_;
  __shared__ unsigned short AsH[4096], AsL[4096], AsO[4096], BsH[4096],
      BsL[4096], Bs2[4096], Bs2L[4096];
  int b = blockIdx.z, tid = threadIdx.x;
  int m0 = blockIdx.y * 128, n0 = blockIdx.x * 128;
  const unsigned short* eH = eHp + (long)b * T_ * E_;
  const unsigned short* eL = eLp + (long)b * T_ * E_;
  const unsigned short* BH = RtHp + (long)b * F_ * E_;
  const unsigned short* BL = RtLp + (long)b * F_ * E_;
  const unsigned short* B2 = R2Hp + (long)b * F_ * E_;
  const unsigned short* B2L = R2Lp + (long)b * F_ * E_;
  int lr = tid & 15, lh = (tid >> 4) & 3, wv = tid >> 6, wr = wv >> 1,
      wc = wv & 1;
  int srow = tid >> 2, sslot = tid & 3;

  f32x4 accC[4][4], accS[4][4];
#pragma unroll
  for (int i = 0; i < 4; i++)
#pragma unroll
    for (int j = 0; j < 4; j++) {
      accC[i][j] = {0.f, 0.f, 0.f, 0.f};
      accS[i][j] = {0.f, 0.f, 0.f, 0.f};
    }

  uint4 ld[12];
  unsigned ow[2];
#pragma unroll
  for (int j = 0; j < 2; j++) {
    long ar = (long)b * T_ + m0 + srow + 64 * j;
    ld[j] = *(const uint4*)&eH[(long)(m0 + srow + 64 * j) * K + sslot * 8];
    ld[2 + j] = *(const uint4*)&eL[(long)(m0 + srow + 64 * j) * K + sslot * 8];
    ow[j] = omb[ar * EW + 0];
    ld[4 + j] = *(const uint4*)&BH[(long)(n0 + srow + 64 * j) * K + sslot * 8];
    ld[6 + j] = *(const uint4*)&BL[(long)(n0 + srow + 64 * j) * K + sslot * 8];
    ld[8 + j] = *(const uint4*)&B2[(long)(n0 + srow + 64 * j) * K + sslot * 8];
    ld[10 + j] = *(const uint4*)&B2L[(long)(n0 + srow + 64 * j) * K + sslot * 8];
  }
  for (int kt = 0; kt < K; kt += 32) {
#pragma unroll
    for (int j = 0; j < 2; j++) {
      int li = (srow + 64 * j) * 32 + sslot * 8;
      *(uint4*)&AsH[li] = ld[j];
      *(uint4*)&AsL[li] = ld[2 + j];
      union { unsigned short us[8]; uint4 v; } ob;
#pragma unroll
      for (int i = 0; i < 8; i++)
        ob.us[i] = ((ow[j] >> (sslot * 8 + i)) & 1) ? (unsigned short)0x3f80 : 0;
      *(uint4*)&AsO[li] = ob.v;
      *(uint4*)&BsH[li] = ld[4 + j];
      *(uint4*)&BsL[li] = ld[6 + j];
      *(uint4*)&Bs2[li] = ld[8 + j];
      *(uint4*)&Bs2L[li] = ld[10 + j];
    }
    __syncthreads();
    if (kt + 32 < K) {
      int k1 = kt + 32;
#pragma unroll
      for (int j = 0; j < 2; j++) {
        long ar = (long)b * T_ + m0 + srow + 64 * j;
        ld[j] = *(const uint4*)&eH[(long)(m0 + srow + 64 * j) * K + k1 + sslot * 8];
        ld[2 + j] = *(const uint4*)&eL[(long)(m0 + srow + 64 * j) * K + k1 + sslot * 8];
        ow[j] = omb[ar * EW + (k1 >> 5)];
        ld[4 + j] = *(const uint4*)&BH[(long)(n0 + srow + 64 * j) * K + k1 + sslot * 8];
        ld[6 + j] = *(const uint4*)&BL[(long)(n0 + srow + 64 * j) * K + k1 + sslot * 8];
        ld[8 + j] = *(const uint4*)&B2[(long)(n0 + srow + 64 * j) * K + k1 + sslot * 8];
        ld[10 + j] = *(const uint4*)&B2L[(long)(n0 + srow + 64 * j) * K + k1 + sslot * 8];
      }
    }
    // phase C: data-fit accumulation (3-MFMA split)
    {
      short8v aH[4], aL[4];
#pragma unroll
      for (int mf = 0; mf < 4; mf++) {
        int ml = wr * 64 + mf * 16 + lr;
        aH[mf] = *(const short8v*)&AsH[ml * 32 + lh * 8];
        aL[mf] = *(const short8v*)&AsL[ml * 32 + lh * 8];
      }
#pragma unroll
      for (int nf = 0; nf < 4; nf++) {
        int nl = wc * 64 + nf * 16 + lr;
        short8v bH = *(const short8v*)&BsH[nl * 32 + lh * 8];
        short8v bL = *(const short8v*)&BsL[nl * 32 + lh * 8];
#pragma unroll
        for (int mf = 0; mf < 4; mf++) {
          accC[mf][nf] = __builtin_amdgcn_mfma_f32_16x16x32_bf16(
              aH[mf], bH, accC[mf][nf], 0, 0, 0);
          accC[mf][nf] = __builtin_amdgcn_mfma_f32_16x16x32_bf16(
              aH[mf], bL, accC[mf][nf], 0, 0, 0);
          accC[mf][nf] = __builtin_amdgcn_mfma_f32_16x16x32_bf16(
              aL[mf], bH, accC[mf][nf], 0, 0, 0);
        }
      }
    }
    // phase S: A_scale accumulation (om exact * R2 hi/lo planes)
    {
      short8v aO[4];
#pragma unroll
      for (int mf = 0; mf < 4; mf++) {
        int ml = wr * 64 + mf * 16 + lr;
        aO[mf] = *(const short8v*)&AsO[ml * 32 + lh * 8];
      }
#pragma unroll
      for (int nf = 0; nf < 4; nf++) {
        int nl = wc * 64 + nf * 16 + lr;
        short8v b2 = *(const short8v*)&Bs2[nl * 32 + lh * 8];
        short8v b2l = *(const short8v*)&Bs2L[nl * 32 + lh * 8];
#pragma unroll
        for (int mf = 0; mf < 4; mf++) {
          accS[mf][nf] = __builtin_amdgcn_mfma_f32_16x16x32_bf16(
              aO[mf], b2, accS[mf][nf], 0, 0, 0);
          accS[mf][nf] = __builtin_amdgcn_mfma_f32_16x16x32_bf16(
              aO[mf], b2l, accS[mf][nf], 0, 0, 0);
        }
      }
    }
    __syncthreads();
  }
  float mu = expf(mu_log[step]);
  float s2 = sigmoidf_(sk[step * 3 + 2]);
#pragma unroll
  for (int mf = 0; mf < 4; mf++)
#pragma unroll
    for (int nf = 0; nf < 4; nf++)
#pragma unroll
      for (int r = 0; r < 4; r++) {
        int m = m0 + wr * 64 + mf * 16 + lh * 4 + r;
        int n = n0 + wc * 64 + nf * 16 + lr;
        long idx = ((long)b * T_ + m) * F_ + n;
        float asc = accS[mf][nf][r];
        float c = accC[mf][nf][r];
        float aold = S0 ? 0.f : (bf2f(AHp[idx]) + bf2f(ALp[idx]));
        float bat = fmaf(asc, aold, c);
        float mag = fmaxf(fabsf(bat) - mu, 0.f);
        float sft = copysignf(mag, bat);
        float ahat = (asc == 0.f) ? 0.f : sft / asc;
        float anew = aold + s2 * (ahat - aold);
        unsigned short h, l;
        split2(anew, h, l);
        AHp[idx] = h;
        ALp[idx] = l;
      }
}

// ---------------------------------------------------------------------------
// P stage 1: lane = e (coalesced), partial sums over a 128-t chunk.
// ---------------------------------------------------------------------------
__global__ __launch_bounds__(256) void p_stage1(
    const unsigned short* __restrict__ eH, const unsigned short* __restrict__ eL,
    const unsigned* __restrict__ omb, const float* __restrict__ Q,
    float* __restrict__ scr) {
  int tc = blockIdx.x, eb = blockIdx.y, b = blockIdx.z;
  int e = eb * 256 + threadIdx.x;
  float Ms[NTRI], rhs[R_];
#pragma unroll
  for (int i = 0; i < NTRI; i++) Ms[i] = 0.f;
#pragma unroll
  for (int i = 0; i < R_; i++) rhs[i] = 0.f;
  for (int t = tc * 128; t < tc * 128 + 128; ++t) {
    const float* qr = Q + ((long)b * T_ + t) * R_;
    float q[R_];
#pragma unroll
    for (int r = 0; r < R_; r++) q[r] = qr[r];
    long row = (long)b * T_ + t;
    long ix = row * E_ + e;
    float ev = bf2f(eH[ix]) + bf2f(eL[ix]);
    unsigned w = omb[row * EW + (e >> 5)];
    float wv = ((w >> (e & 31)) & 1) ? 1.f : 0.f;
    float wq[R_];
#pragma unroll
    for (int r = 0; r < R_; r++) {
      wq[r] = wv * q[r];
      rhs[r] = fmaf(ev, q[r], rhs[r]);
    }
    int idx = 0;
#pragma unroll
    for (int r = 0; r < R_; r++)
#pragma unroll
      for (int s = 0; s <= r; s++) {
        Ms[idx] = fmaf(wq[r], q[s], Ms[idx]);
        idx++;
      }
  }
  long so = ((long)b * 16 + tc) * 65 * E_ + e;
#pragma unroll
  for (int i = 0; i < NTRI; i++) scr[so + (long)i * E_] = Ms[i];
#pragma unroll
  for (int i = 0; i < R_; i++) scr[so + (long)(NTRI + i) * E_] = rhs[i];
}

__global__ __launch_bounds__(256) void p_stage2(
    const float* __restrict__ scr, const float* __restrict__ Pin,
    float* __restrict__ Pout, const float* __restrict__ lam_log,
    const float* __restrict__ sk, int step) {
  int idx = blockIdx.x * 256 + threadIdx.x;
  int b = idx >> 9, e = idx & 511;
  float Ms[NTRI], rhs[R_], x[R_];
#pragma unroll
  for (int i = 0; i < NTRI; i++) Ms[i] = 0.f;
#pragma unroll
  for (int i = 0; i < R_; i++) rhs[i] = 0.f;
  for (int tc = 0; tc < 16; ++tc) {
    long so = ((long)b * 16 + tc) * 65 * E_ + e;
#pragma unroll
    for (int i = 0; i < NTRI; i++) Ms[i] += scr[so + (long)i * E_];
#pragma unroll
    for (int i = 0; i < R_; i++) rhs[i] += scr[so + (long)(NTRI + i) * E_];
  }
  float lam = expf(lam_log[step]);
  solve10(Ms, rhs, lam, x);
  float s0 = sigmoidf_(sk[step * 3 + 0]);
#pragma unroll
  for (int r = 0; r < R_; r++) {
    float pold = Pin[(long)idx * R_ + r];
    Pout[(long)idx * R_ + r] = pold + s0 * (x[r] - pold);
  }
}

// ---------------------------------------------------------------------------
// Q stage 1: LDS-tiled. Stage 256t x 16e chunks coalesced, compute per-t.
// ---------------------------------------------------------------------------
__global__ __launch_bounds__(256) void q_stage1(
    const unsigned short* __restrict__ eH, const unsigned short* __restrict__ eL,
    const unsigned* __restrict__ omb, const float* __restrict__ Pn,
    float* __restrict__ scr) {
  __shared__ float et[256][17], ot[256][17];
  int ec = blockIdx.x, tb = blockIdx.y, b = blockIdx.z;
  int tid = threadIdx.x;
  int t = tb * 256 + tid;
  float Ms[NTRI], rhs[R_];
#pragma unroll
  for (int i = 0; i < NTRI; i++) Ms[i] = 0.f;
#pragma unroll
  for (int i = 0; i < R_; i++) rhs[i] = 0.f;
  int eq = tid & 3, tl = tid >> 2;
  for (int ch = 0; ch < 8; ++ch) {
    int e0 = ec * 128 + ch * 16;
    __syncthreads();
#pragma unroll
    for (int p = 0; p < 4; p++) {
      int ts = tl + 64 * p;
      long row = (long)b * T_ + tb * 256 + ts;
      long ix = row * E_ + e0 + eq * 4;
      ushort4 hv = *(const ushort4*)&eH[ix];
      ushort4 lv = *(const ushort4*)&eL[ix];
      unsigned w = omb[row * EW + ((e0 + eq * 4) >> 5)];
      int bb = (e0 + eq * 4) & 31;
      et[ts][eq * 4 + 0] = bf2f(hv.x) + bf2f(lv.x);
      et[ts][eq * 4 + 1] = bf2f(hv.y) + bf2f(lv.y);
      et[ts][eq * 4 + 2] = bf2f(hv.z) + bf2f(lv.z);
      et[ts][eq * 4 + 3] = bf2f(hv.w) + bf2f(lv.w);
      ot[ts][eq * 4 + 0] = ((w >> (bb + 0)) & 1) ? 1.f : 0.f;
      ot[ts][eq * 4 + 1] = ((w >> (bb + 1)) & 1) ? 1.f : 0.f;
      ot[ts][eq * 4 + 2] = ((w >> (bb + 2)) & 1) ? 1.f : 0.f;
      ot[ts][eq * 4 + 3] = ((w >> (bb + 3)) & 1) ? 1.f : 0.f;
    }
    __syncthreads();
    for (int ee = 0; ee < 16; ++ee) {
      int e = e0 + ee;
      const float* pr = Pn + ((long)b * E_ + e) * R_;
      float p10[R_];
#pragma unroll
      for (int r = 0; r < R_; r++) p10[r] = pr[r];
      float wv = ot[tid][ee], ev = et[tid][ee];
      float wp[R_];
#pragma unroll
      for (int r = 0; r < R_; r++) {
        wp[r] = wv * p10[r];
        rhs[r] = fmaf(ev, p10[r], rhs[r]);
      }
      int idx = 0;
#pragma unroll
      for (int r = 0; r < R_; r++)
#pragma unroll
        for (int s = 0; s <= r; s++) {
          Ms[idx] = fmaf(wp[r], p10[s], Ms[idx]);
          idx++;
        }
    }
  }
  long so = ((long)b * 4 + ec) * 65 * T_ + t;
#pragma unroll
  for (int i = 0; i < NTRI; i++) scr[so + (long)i * T_] = Ms[i];
#pragma unroll
  for (int i = 0; i < R_; i++) scr[so + (long)(NTRI + i) * T_] = rhs[i];
}

__global__ __launch_bounds__(256) void q_stage2(
    const float* __restrict__ scr, const float* __restrict__ Qin,
    float* __restrict__ Qout, const float* __restrict__ lam_log,
    const float* __restrict__ sk, int step) {
  int idx = blockIdx.x * 256 + threadIdx.x;
  int b = idx >> 11, t = idx & 2047;
  float Ms[NTRI], rhs[R_];
#pragma unroll
  for (int i = 0; i < NTRI; i++) Ms[i] = 0.f;
#pragma unroll
  for (int i = 0; i < R_; i++) rhs[i] = 0.f;
  for (int ec = 0; ec < 4; ++ec) {
    long so = ((long)b * 4 + ec) * 65 * T_ + t;
#pragma unroll
    for (int i = 0; i < NTRI; i++) Ms[i] += scr[so + (long)i * T_];
#pragma unroll
    for (int i = 0; i < R_; i++) rhs[i] += scr[so + (long)(NTRI + i) * T_];
  }
  float lam = expf(lam_log[step]);
  float x2[R_];
  solve10(Ms, rhs, lam, x2);
  float s1 = sigmoidf_(sk[step * 3 + 1]);
#pragma unroll
  for (int r = 0; r < R_; r++) {
    float qold = Qin[(long)idx * R_ + r];
    Qout[(long)idx * R_ + r] = qold + s1 * (x2[r] - qold);
  }
}

// ---------------------------------------------------------------------------
// datafit: err_out[t,e] = err_in[t,e] - om*dot(P[e],Q[t]); planes in/out
// ---------------------------------------------------------------------------
__global__ __launch_bounds__(256) void datafit_k(
    const unsigned short* __restrict__ inH, const unsigned short* __restrict__ inL,
    unsigned short* __restrict__ outH, unsigned short* __restrict__ outL,
    const unsigned* __restrict__ omb, const float* __restrict__ Pn,
    const float* __restrict__ Qn) {
  int tc = blockIdx.x, eb = blockIdx.y, b = blockIdx.z;
  int e = eb * 256 + threadIdx.x;
  float p[R_];
#pragma unroll
  for (int r = 0; r < R_; r++) p[r] = Pn[((long)b * E_ + e) * R_ + r];
  for (int t = tc * 16; t < tc * 16 + 16; ++t) {
    const float* qr = Qn + ((long)b * T_ + t) * R_;
    float dot = 0.f;
#pragma unroll
    for (int r = 0; r < R_; r++) dot = fmaf(p[r], qr[r], dot);
    long row = (long)b * T_ + t;
    long ix = row * E_ + e;
    unsigned w = omb[row * EW + (e >> 5)];
    float om = ((w >> (e & 31)) & 1) ? 1.f : 0.f;
    float er = (bf2f(inH[ix]) + bf2f(inL[ix])) - om * dot;
    unsigned short h, l;
    split2(er, h, l);
    outH[ix] = h;
    outL[ix] = l;
  }
}

// ---------------------------------------------------------------------------
// Prepass kernels
// ---------------------------------------------------------------------------
__global__ __launch_bounds__(256) void bitpack_om(const float* __restrict__ Om,
                                                  unsigned* __restrict__ omb) {
  __shared__ float tl[128][65];
  int t0 = blockIdx.x * 64, e0 = blockIdx.y * 128, b = blockIdx.z;
  int tid = threadIdx.x;
  for (int j = 0; j < 32; j++) {
    int idx = tid + 256 * j;
    int el = idx >> 6, tloc = idx & 63;
    tl[el][tloc] = Om[((long)b * E_ + e0 + el) * T_ + t0 + tloc];
  }
  __syncthreads();
  int tloc = tid & 63, wg = tid >> 6;
  unsigned w = 0;
  for (int i = 0; i < 32; i++)
    w |= (tl[wg * 32 + i][tloc] != 0.f ? 1u : 0u) << i;
  omb[((long)b * T_ + t0 + tloc) * EW + e0 / 32 + wg] = w;
}

__global__ __launch_bounds__(256) void transpack_y(
    const float* __restrict__ Y, const float* __restrict__ Om,
    unsigned short* __restrict__ YH, unsigned short* __restrict__ YL) {
  __shared__ float tile[32][33];
  int c0 = blockIdx.x * 32, r0 = blockIdx.y * 32, b = blockIdx.z;  // c:T r:E
  int tid = threadIdx.x;
  int c4 = (tid & 7) << 2, r = tid >> 3;
  long ib = (long)b * E_ * T_;
  float4 v = *(const float4*)&Y[ib + (long)(r0 + r) * T_ + c0 + c4];
  float4 w = *(const float4*)&Om[ib + (long)(r0 + r) * T_ + c0 + c4];
  tile[r][c4 + 0] = v.x * w.x;
  tile[r][c4 + 1] = v.y * w.y;
  tile[r][c4 + 2] = v.z * w.z;
  tile[r][c4 + 3] = v.w * w.w;
  __syncthreads();
  int co = tid >> 3, ro4 = (tid & 7) << 2;
  ushort4 h, l;
  split2(tile[ro4 + 0][co], h.x, l.x);
  split2(tile[ro4 + 1][co], h.y, l.y);
  split2(tile[ro4 + 2][co], h.z, l.z);
  split2(tile[ro4 + 3][co], h.w, l.w);
  long ob = ((long)b * T_ + c0 + co) * E_ + r0 + ro4;
  *(ushort4*)&YH[ob] = h;
  *(ushort4*)&YL[ob] = l;
}

__global__ __launch_bounds__(256) void transpack_r(
    const float* __restrict__ Rm, unsigned short* __restrict__ RtH,
    unsigned short* __restrict__ RtL, unsigned short* __restrict__ R2H,
    unsigned short* __restrict__ R2L) {
  __shared__ float tile[32][33];
  int c0 = blockIdx.x * 32, r0 = blockIdx.y * 32, b = blockIdx.z;  // c:F r:E
  int tid = threadIdx.x;
  int c4 = (tid & 7) << 2, r = tid >> 3;
  long ib = (long)b * E_ * F_;
  float4 v = *(const float4*)&Rm[ib + (long)(r0 + r) * F_ + c0 + c4];
  tile[r][c4 + 0] = v.x;
  tile[r][c4 + 1] = v.y;
  tile[r][c4 + 2] = v.z;
  tile[r][c4 + 3] = v.w;
  __syncthreads();
  int co = tid >> 3, ro4 = (tid & 7) << 2;
  ushort4 h, l, s, sl;
  float a0 = tile[ro4 + 0][co], a1 = tile[ro4 + 1][co];
  float a2 = tile[ro4 + 2][co], a3 = tile[ro4 + 3][co];
  split2(a0, h.x, l.x);
  split2(a1, h.y, l.y);
  split2(a2, h.z, l.z);
  split2(a3, h.w, l.w);
  split2(a0 * a0, s.x, sl.x);
  split2(a1 * a1, s.y, sl.y);
  split2(a2 * a2, s.z, sl.z);
  split2(a3 * a3, s.w, sl.w);
  long ob = ((long)b * F_ + c0 + co) * E_ + r0 + ro4;
  *(ushort4*)&RtH[ob] = h;
  *(ushort4*)&RtL[ob] = l;
  *(ushort4*)&R2H[ob] = s;
  *(ushort4*)&R2L[ob] = sl;
}

__global__ __launch_bounds__(256) void pack_rm(const float* __restrict__ Rm,
                                               unsigned short* __restrict__ RmH,
                                               unsigned short* __restrict__ RmL) {
  long i = ((long)blockIdx.x * 256 + threadIdx.x) * 4;
  float4 v = *(const float4*)&Rm[i];
  ushort4 h, l;
  split2(v.x, h.x, l.x);
  split2(v.y, h.y, l.y);
  split2(v.z, h.z, l.z);
  split2(v.w, h.w, l.w);
  *(ushort4*)&RmH[i] = h;
  *(ushort4*)&RmL[i] = l;
}

__global__ __launch_bounds__(256) void trans_out(
    const unsigned short* __restrict__ AH, const unsigned short* __restrict__ AL,
    float* __restrict__ outA) {
  __shared__ float tile[32][33];
  int c0 = blockIdx.x * 32, r0 = blockIdx.y * 32, b = blockIdx.z;  // c:F r:T
  int tid = threadIdx.x;
  int c4 = (tid & 7) << 2, r = tid >> 3;
  long ib = (long)b * T_ * F_;
  ushort4 h = *(const ushort4*)&AH[ib + (long)(r0 + r) * F_ + c0 + c4];
  ushort4 l = *(const ushort4*)&AL[ib + (long)(r0 + r) * F_ + c0 + c4];
  tile[r][c4 + 0] = bf2f(h.x) + bf2f(l.x);
  tile[r][c4 + 1] = bf2f(h.y) + bf2f(l.y);
  tile[r][c4 + 2] = bf2f(h.z) + bf2f(l.z);
  tile[r][c4 + 3] = bf2f(h.w) + bf2f(l.w);
  __syncthreads();
  int co = tid >> 3, ro4 = (tid & 7) << 2;
  float4 o;
  o.x = tile[ro4 + 0][co];
  o.y = tile[ro4 + 1][co];
  o.z = tile[ro4 + 2][co];
  o.w = tile[ro4 + 3][co];
  *(float4*)&outA[(long)b * F_ * T_ + (long)(c0 + co) * T_ + r0 + ro4] = o;
}

// ---------------------------------------------------------------------------
extern "C" void kernel_launch(void* const* d_in, const int* in_sizes, int n_in,
                              void* d_out, int out_size, void* d_ws,
                              size_t ws_size, hipStream_t stream) {
  const float* Y = (const float*)d_in[0];
  const float* Rm = (const float*)d_in[1];
  const float* Om = (const float*)d_in[2];
  const float* P0 = (const float*)d_in[3];
  const float* Q0 = (const float*)d_in[4];
  const float* lam_log = (const float*)d_in[6];
  const float* mu_log = (const float*)d_in[7];
  const float* sk = (const float*)d_in[8];

  char* w = (char*)d_ws;
  float* scr = (float*)w;                     w += 17039360;
  float* Pa = (float*)w;                      w += 163840;
  float* Pb = (float*)w;                      w += 163840;
  float* Qa = (float*)w;                      w += 655360;
  float* Qb = (float*)w;                      w += 655360;
  unsigned short* YH = (unsigned short*)w;    w += 16777216;
  unsigned short* YL = (unsigned short*)w;    w += 16777216;
  unsigned short* eH = (unsigned short*)w;    w += 16777216;
  unsigned short* eL = (unsigned short*)w;    w += 16777216;
  unsigned* OmB = (unsigned*)w;               w += 1048576;
  unsigned short* RmH = (unsigned short*)w;   w += 8388608;
  unsigned short* RmL = (unsigned short*)w;   w += 8388608;
  unsigned short* RtH = (unsigned short*)w;   w += 8388608;
  unsigned short* RtL = (unsigned short*)w;   w += 8388608;
  unsigned short* R2H = (unsigned short*)w;   w += 8388608;
  unsigned short* R2L = (unsigned short*)w;   w += 8388608;
  unsigned short* AH = (unsigned short*)w;    w += 33554432;
  unsigned short* AL = (unsigned short*)w;    w += 33554432;

  float* outP = (float*)d_out;
  float* outQ = outP + B_ * E_ * R_;
  float* outA = outQ + B_ * T_ * R_;

  const float* Pr[L_] = {P0, Pa, Pb, Pa, Pb};
  float* Pw[L_] = {Pa, Pb, Pa, Pb, outP};
  const float* Qr[L_] = {Q0, Qa, Qb, Qa, Qb};
  float* Qw[L_] = {Qa, Qb, Qa, Qb, outQ};

  dim3 blk(256);
  bitpack_om<<<dim3(T_ / 64, E_ / 128, B_), blk, 0, stream>>>(Om, OmB);
  transpack_y<<<dim3(T_ / 32, E_ / 32, B_), blk, 0, stream>>>(Y, Om, YH, YL);
  pack_rm<<<(B_ * E_ * F_) / 1024, blk, 0, stream>>>(Rm, RmH, RmL);
  transpack_r<<<dim3(F_ / 32, E_ / 32, B_), blk, 0, stream>>>(Rm, RtH, RtL,
                                                              R2H, R2L);

  for (int s = 0; s < L_; ++s) {
    const unsigned short* pH = s ? eH : YH;
    const unsigned short* pL = s ? eL : YL;
    if (s) {
      gemm_err<<<dim3(E_ / 128, T_ / 128, B_), blk, 0, stream>>>(
          AH, AL, RmH, RmL, YH, YL, OmB, eH, eL);
    }
    p_stage1<<<dim3(16, 2, B_), blk, 0, stream>>>(pH, pL, OmB, Qr[s], scr);
    p_stage2<<<16, blk, 0, stream>>>(scr, Pr[s], Pw[s], lam_log, sk, s);
    q_stage1<<<dim3(4, 8, B_), blk, 0, stream>>>(pH, pL, OmB, Pw[s], scr);
    q_stage2<<<64, blk, 0, stream>>>(scr, Qr[s], Qw[s], lam_log, sk, s);
    datafit_k<<<dim3(128, 2, B_), blk, 0, stream>>>(pH, pL, eH, eL, OmB, Pw[s],
                                                    Qw[s]);
    if (s == 0)
      gemm_aupd<1><<<dim3(F_ / 128, T_ / 128, B_), blk, 0, stream>>>(
          eH, eL, OmB, RtH, RtL, R2H, R2L, AH, AL, mu_log, sk, 0);
    else
      gemm_aupd<0><<<dim3(F_ / 128, T_ / 128, B_), blk, 0, stream>>>(
          eH, eL, OmB, RtH, RtL, R2H, R2L, AH, AL, mu_log, sk, s);
  }
  trans_out<<<dim3(F_ / 32, T_ / 32, B_), blk, 0, stream>>>(AH, AL, outA);
}